// Round 4
// baseline (399.278 us; speedup 1.0000x reference)
//
#include <hip/hip_runtime.h>
#include <hip/hip_bf16.h>
#include <math.h>

#define Nn 32
#define Dd 512
#define Pp 4096
#define Kk 64
#define SEG 16           // p-segments (blocks per n)
#define PXB 256          // px per block
#define PT 64            // px per p-tile
static constexpr float EPSF = 1e-12f;

typedef short short8 __attribute__((ext_vector_type(8)));
typedef short short4v __attribute__((ext_vector_type(4)));
typedef float floatx4 __attribute__((ext_vector_type(4)));

static __device__ __forceinline__ int f2b2(float a, float b) {
  __hip_bfloat162 h = __float22bfloat162_rn(float2{a, b});
  int r; __builtin_memcpy(&r, &h, 4); return r;
}
static __device__ __forceinline__ short8 pack8(const float* v) {
  union { short8 s; int i[4]; } u;
  u.i[0] = f2b2(v[0], v[1]); u.i[1] = f2b2(v[2], v[3]);
  u.i[2] = f2b2(v[4], v[5]); u.i[3] = f2b2(v[6], v[7]);
  return u.s;
}
static __device__ __forceinline__ short f2b1(float f) {
  unsigned u = __float_as_uint(f);
  return (short)((u + 0x7FFFu + ((u >> 16) & 1u)) >> 16);
}
static __device__ __forceinline__ float b2f(short s) {
  return __uint_as_float(((unsigned)(unsigned short)s) << 16);
}

// ---------------------------------------------------------------------------
// K0: prepack w -> bf16 B-fragment order wp[chunk][k][q][8] + zero asum.
// ---------------------------------------------------------------------------
__global__ __launch_bounds__(256) void k_wpack(
    const float* __restrict__ w, float* __restrict__ asum,
    short* __restrict__ wp)
{
  int id = blockIdx.x * 256 + threadIdx.x;     // 4*256 = 1024 threads
  if (id >= 1024) return;
  asum[id] = 0.f; asum[id + 1024] = 0.f;       // zero asum[2048]
  int chunk = id >> 6, k = id & 63;
  const float* src = w + (size_t)k * Dd + chunk * 32;
  short* dst = wp + ((size_t)(chunk * 64 + k)) * 32;
#pragma unroll
  for (int q = 0; q < 4; ++q) {
    float v[8];
    *(float4*)&v[0] = *(const float4*)(src + q * 8);
    *(float4*)&v[4] = *(const float4*)(src + q * 8 + 4);
    *(short8*)(dst + q * 8) = pack8(v);
  }
}

// ---------------------------------------------------------------------------
// K1: FUSED norm + logits + softmax + vlad-partial.
// grid: 32 n x 16 segs = 512 blocks x 256 thr; 2 blocks/CU.
// launch_bounds(256,2): 2 waves/SIMD -> 256-reg/wave budget (round-2 showed
// a tighter bound register-starves the load pipeliner: 242us, all idle).
// Per 64-px tile: GEMM1 (A = x scalar loads, B = wp bf16, L1/L2-hot) with x
// simultaneously re-read as float4 (L1-hot) and stashed bf16 in LDS xb
// (XOR-swizzled cols). Softmax in-register per wave, max-less (logits
// bounded by ||w_k|| ~ 1.13, exp-safe); a*inv -> LDS a_s. GEMM2 from LDS
// only, acc [64k x 128d] per wave in VGPRs across all 4 tiles.
// Epilogue: acc2 repacked through xb (dead after last GEMM2) so vpart is
// written as 16B/lane row-complete stores (round-2 counters showed 2.2x
// write amplification from scattered 2B stores: 74 MB vs 33.5 ideal).
// ---------------------------------------------------------------------------
__global__ __launch_bounds__(256, 2) void k_fused(
    const float* __restrict__ x, const short* __restrict__ wp,
    float* __restrict__ asum, short* __restrict__ vpart)
{
  constexpr int XS = 64;   // xb row stride (shorts), XOR-swizzled columns
  constexpr int AS = 72;   // a_s row stride (16B-aligned rows)
  __shared__ short xb[Dd * XS];      // 64 KB  x tile bf16 [d][px] swizzled
  __shared__ short as_[Kk * AS];     // 9 KB   a*inv bf16  [k][px]
  __shared__ float invs[PT];

  const int tid = threadIdx.x;
  const int n = blockIdx.x >> 4, seg = blockIdx.x & 15;
  const int wave = tid >> 6, lane = tid & 63;
  const int q = lane >> 4, pc = lane & 15;
  const int sd = tid >> 3, sc = tid & 7;           // stage loader coords
  const int swc = (sc * 8) ^ ((sd & 7) << 3);      // swizzled stage col
  const int rdxor = (pc & 7) << 3;                 // swizzle for GEMM2 reads

  floatx4 acc2[4][8];                // [k-tile][d-tile] = 128 regs
#pragma unroll
  for (int t = 0; t < 4; ++t)
#pragma unroll
    for (int s2 = 0; s2 < 8; ++s2) acc2[t][s2] = floatx4{0.f, 0.f, 0.f, 0.f};
  float asr[4] = {0.f, 0.f, 0.f, 0.f};   // asum partials (k = t*16+pc)

  const float* xn = x + (size_t)n * Dd * Pp;

  for (int pt = 0; pt < PXB / PT; ++pt) {
    const int p0 = seg * PXB + pt * PT;
    __syncthreads();                 // xb/a_s free to overwrite

    floatx4 acc1[4];
#pragma unroll
    for (int t = 0; t < 4; ++t) acc1[t] = floatx4{0.f, 0.f, 0.f, 0.f};
    float sq = 0.f;

    const float* xa = xn + (size_t)(q * 8) * Pp + p0 + wave * 16 + pc;
    const float* xs = xn + (size_t)sd * Pp + p0 + sc * 8;

    for (int dc = 0; dc < Dd; dc += 32) {
      // stage: re-read (L1-hot) as float4, stash bf16 tile [d][px] swizzled
      float4 u0 = *(const float4*)xs;
      float4 u1 = *(const float4*)(xs + 4);
      int2 w0 = { f2b2(u0.x, u0.y), f2b2(u0.z, u0.w) };
      int2 w1 = { f2b2(u1.x, u1.y), f2b2(u1.z, u1.w) };
      *(int2*)&xb[(dc + sd) * XS + swc] = w0;
      *(int2*)&xb[(dc + sd) * XS + swc + 4] = w1;
      xs += (size_t)32 * Pp;
      // A-frag: 8 scalar x loads (coalesced 64B segments), ssq piggyback
      float v[8];
#pragma unroll
      for (int j = 0; j < 8; ++j) {
        float a = xa[(size_t)j * Pp];
        v[j] = a; sq += a * a;
      }
      xa += (size_t)32 * Pp;
      short8 af = pack8(v);
      // B-frags from prepacked w (L2-hot) + MFMA
      const short* wc = wp + (size_t)(dc >> 5) * 2048 + pc * 32 + q * 8;
#pragma unroll
      for (int t = 0; t < 4; ++t) {
        short8 bf = *(const short8*)(wc + t * 512);
        acc1[t] = __builtin_amdgcn_mfma_f32_16x16x32_bf16(af, bf, acc1[t], 0, 0, 0);
      }
    }

    // per-pixel inv-norm (lane pc owns px = wave*16+pc partial over its q-quarter)
    {
      float tsum = sq;
      tsum += __shfl_xor(tsum, 16);
      tsum += __shfl_xor(tsum, 32);
      if (q == 0) invs[wave * 16 + pc] = 1.f / fmaxf(sqrtf(tsum), EPSF);
    }
    float ivr[4];
#pragma unroll
    for (int r = 0; r < 4; ++r) ivr[r] = invs[wave * 16 + q * 4 + r];

    // softmax over k per C-row (row = px = q*4+r, col = k = t*16+pc).
    // Max-less: |logit| <= ||w_k|| ~ 1.13, exp range [0.32, 3.1] -- safe and
    // mathematically identical to the shifted form.
#pragma unroll
    for (int r = 0; r < 4; ++r) {
      float e[4], sm = 0.f;
#pragma unroll
      for (int t = 0; t < 4; ++t) {
        e[t] = __expf(acc1[t][r] * ivr[r]);
        sm += e[t];
      }
      sm += __shfl_xor(sm, 1);
      sm += __shfl_xor(sm, 2);
      sm += __shfl_xor(sm, 4);
      sm += __shfl_xor(sm, 8);
      float si = 1.f / sm;
#pragma unroll
      for (int t = 0; t < 4; ++t) {
        float av = e[t] * si;                 // plain a
        asr[t] += av;
        as_[(t * 16 + pc) * AS + wave * 16 + q * 4 + r] = f2b1(av * ivr[r]);
      }
    }
    __syncthreads();                          // xb + a_s complete

    // GEMM2: vlad acc += a_s[k][p] * xb[d][p], all from LDS (b128 frags,
    // xb reads XOR-deswizzled: row&7 == pc&7 on both write and read sides)
#pragma unroll
    for (int c = 0; c < 2; ++c) {             // px-chunks of 32
      short8 af2[4];
#pragma unroll
      for (int t = 0; t < 4; ++t)
        af2[t] = *(const short8*)&as_[(t * 16 + pc) * AS + c * 32 + q * 8];
#pragma unroll
      for (int s2 = 0; s2 < 8; ++s2) {
        const int row = wave * 128 + s2 * 16 + pc;
        short8 bf2 = *(const short8*)&xb[row * XS + ((c * 32 + q * 8) ^ rdxor)];
#pragma unroll
        for (int t = 0; t < 4; ++t)
          acc2[t][s2] = __builtin_amdgcn_mfma_f32_16x16x32_bf16(
              af2[t], bf2, acc2[t][s2], 0, 0, 0);
      }
    }
  }

  // epilogue: asum atomics
#pragma unroll
  for (int t = 0; t < 4; ++t) {
    float v = asr[t];
    v += __shfl_xor(v, 16);
    v += __shfl_xor(v, 32);
    if (q == 0) atomicAdd(&asum[n * Kk + t * 16 + pc], v);
  }

  // epilogue: repack acc2 through xb (dead) -> row-complete short8 stores.
  // Stage layout sxb[k][d ^ ((k&7)<<3)] (xor 8-short-aligned: spreads banks,
  // preserves 16B-aligned b128 readback).
  __syncthreads();                 // all GEMM2 reads of xb done
#pragma unroll
  for (int t = 0; t < 4; ++t)
#pragma unroll
    for (int s2 = 0; s2 < 8; ++s2)
#pragma unroll
      for (int r = 0; r < 4; ++r) {
        const int k = t * 16 + q * 4 + r;
        const int d = wave * 128 + s2 * 16 + pc;
        xb[k * Dd + (d ^ ((k & 7) << 3))] = f2b1(acc2[t][s2][r]);
      }
  __syncthreads();                 // stage complete
  short* vb = vpart + ((size_t)(seg * Nn + n) * Kk) * Dd;
#pragma unroll
  for (int i = 0; i < 16; ++i) {
    const int k = i * 4 + wave;    // each wave streams rows k = i*4+wave
    const int d = lane * 8;        // 16B/lane, 1KB/instr, line-complete
    short8 val = *(const short8*)&xb[k * Dd + (d ^ ((k & 7) << 3))];
    *(short8*)&vb[(size_t)k * Dd + d] = val;
  }
}

// ---------------------------------------------------------------------------
// K2: combine 16 bf16 partials, subtract asum*centroid, intra-normalize,
// fold global 1/sqrt(K)=0.125 (rows are unit-norm after intra-normalization,
// so the global L2 norm is exactly sqrt(K)). grid: Nn*Kk blocks x 64 thr
// (1 wave: short8 16B loads, pure shfl reduction, no LDS/barrier).
// ---------------------------------------------------------------------------
__global__ __launch_bounds__(64) void k_intra(
    const short* __restrict__ vpart, const float* __restrict__ asum,
    const float* __restrict__ cent, float* __restrict__ out)
{
  const int nk = blockIdx.x;
  const int n = nk >> 6, k = nk & 63;
  const int tid = threadIdx.x;     // 0..63
  const int d = tid * 8;

  float v[8] = {0.f, 0.f, 0.f, 0.f, 0.f, 0.f, 0.f, 0.f};
#pragma unroll
  for (int ps = 0; ps < SEG; ++ps) {
    short8 t8 = *(const short8*)&vpart[((size_t)(ps * Nn + n) * Kk + k) * Dd + d];
#pragma unroll
    for (int j = 0; j < 8; ++j) v[j] += b2f(t8[j]);
  }
  float s = asum[n * Kk + k];
  float4 c0 = *(const float4*)&cent[(size_t)k * Dd + d];
  float4 c1 = *(const float4*)&cent[(size_t)k * Dd + d + 4];
  v[0] -= s * c0.x; v[1] -= s * c0.y; v[2] -= s * c0.z; v[3] -= s * c0.w;
  v[4] -= s * c1.x; v[5] -= s * c1.y; v[6] -= s * c1.z; v[7] -= s * c1.w;

  float qq = 0.f;
#pragma unroll
  for (int j = 0; j < 8; ++j) qq += v[j] * v[j];
#pragma unroll
  for (int off = 32; off; off >>= 1) qq += __shfl_xor(qq, off);
  float norm = sqrtf(qq);
  float r = 0.125f / fmaxf(norm, EPSF);   // intra-norm * global 1/sqrt(64)
  float* ob = &out[(size_t)n * (Kk * Dd) + (size_t)k * Dd + d];
  *(float4*)ob       = float4{v[0] * r, v[1] * r, v[2] * r, v[3] * r};
  *(float4*)(ob + 4) = float4{v[4] * r, v[5] * r, v[6] * r, v[7] * r};
}

extern "C" void kernel_launch(void* const* d_in, const int* in_sizes, int n_in,
                              void* d_out, int out_size, void* d_ws, size_t ws_size,
                              hipStream_t stream) {
  (void)in_sizes; (void)n_in; (void)out_size; (void)ws_size;
  const float* x    = (const float*)d_in[0];   // [N,D,H,W]
  const float* w    = (const float*)d_in[1];   // [K,D]
  const float* cent = (const float*)d_in[2];   // [K,D]
  float* out = (float*)d_out;

  // ws: asum f32[2048] | vpart bf16 [SEG*N*K*D] (33.5 MB) | wp bf16
  float* asum  = (float*)d_ws;
  short* vpart = (short*)(asum + Nn * Kk);
  short* wpk   = vpart + (size_t)SEG * Nn * Kk * Dd;

  k_wpack<<<4, 256, 0, stream>>>(w, asum, wpk);
  k_fused<<<Nn * SEG, 256, 0, stream>>>(x, wpk, asum, vpart);
  k_intra<<<Nn * Kk, 64, 0, stream>>>(vpart, asum, cent, out);
}

// Round 5
// 385.997 us; speedup vs baseline: 1.0344x; 1.0344x over previous
//
#include <hip/hip_runtime.h>
#include <hip/hip_bf16.h>
#include <math.h>

#define Nn 32
#define Dd 512
#define Pp 4096
#define Kk 64
#define SEG 8            // p-segments (blocks per n)
#define PXB 512          // px per block
#define PT 128           // px per p-tile
static constexpr float EPSF = 1e-12f;

typedef short short8 __attribute__((ext_vector_type(8)));
typedef short short4v __attribute__((ext_vector_type(4)));
typedef float floatx4 __attribute__((ext_vector_type(4)));

static __device__ __forceinline__ int f2b2(float a, float b) {
  __hip_bfloat162 h = __float22bfloat162_rn(float2{a, b});
  int r; __builtin_memcpy(&r, &h, 4); return r;
}
static __device__ __forceinline__ short8 pack8(const float* v) {
  union { short8 s; int i[4]; } u;
  u.i[0] = f2b2(v[0], v[1]); u.i[1] = f2b2(v[2], v[3]);
  u.i[2] = f2b2(v[4], v[5]); u.i[3] = f2b2(v[6], v[7]);
  return u.s;
}
static __device__ __forceinline__ short f2b1(float f) {
  unsigned u = __float_as_uint(f);
  return (short)((u + 0x7FFFu + ((u >> 16) & 1u)) >> 16);
}
static __device__ __forceinline__ float b2f(short s) {
  return __uint_as_float(((unsigned)(unsigned short)s) << 16);
}

// ---------------------------------------------------------------------------
// K0: prepack w -> bf16 B-fragment order wp[chunk][k][q][8] + zero asum.
// ---------------------------------------------------------------------------
__global__ __launch_bounds__(256) void k_wpack(
    const float* __restrict__ w, float* __restrict__ asum,
    short* __restrict__ wp)
{
  int id = blockIdx.x * 256 + threadIdx.x;     // 4*256 = 1024 threads
  if (id >= 1024) return;
  asum[id] = 0.f; asum[id + 1024] = 0.f;       // zero asum[2048]
  int chunk = id >> 6, k = id & 63;
  const float* src = w + (size_t)k * Dd + chunk * 32;
  short* dst = wp + ((size_t)(chunk * 64 + k)) * 32;
#pragma unroll
  for (int q = 0; q < 4; ++q) {
    float v[8];
    *(float4*)&v[0] = *(const float4*)(src + q * 8);
    *(float4*)&v[4] = *(const float4*)(src + q * 8 + 4);
    *(short8*)(dst + q * 8) = pack8(v);
  }
}

// ---------------------------------------------------------------------------
// K1: FUSED norm + logits + softmax + vlad-partial.
// grid: 32 n x 8 segs = 256 blocks x 512 thr (8 waves); 1 block/CU.
// launch_bounds(512,2): 8 waves/block / 4 EU = 2 waves/EU -> full 256-reg
// budget per wave (round-2 lesson: tighter caps starve the load pipeliner).
// TLP identical to the SEG=16 version (8 waves/CU) but: half the vpart
// round-trip (16.8 MB), half the barriers per px, acc2 halves to 64 VGPRs.
// Per 128-px tile: GEMM1 (A = x scalar loads, B = wp bf16) with x
// simultaneously re-read as float4 (L1-hot) and stashed bf16 in LDS xb
// (XOR-swizzled cols). Softmax in-register, fully in-wave, max-less
// (|logit| <= ||w_k|| ~ 1.13, exp-safe). GEMM2 from LDS only; per-wave
// acc [64k x 64d] held in VGPRs across all 4 tiles.
// Epilogue: acc2 repacked through xb (dead) -> row-complete short8 stores.
// ---------------------------------------------------------------------------
__global__ __launch_bounds__(512, 2) void k_fused(
    const float* __restrict__ x, const short* __restrict__ wp,
    float* __restrict__ asum, short* __restrict__ vpart)
{
  constexpr int XS = 128;  // xb row stride (shorts), XOR-swizzled columns
  constexpr int AS = 136;  // a_s row stride (16B-aligned rows)
  __shared__ short xb[Dd * XS];      // 128 KB x tile bf16 [d][px] swizzled
  __shared__ short as_[Kk * AS];     // 17 KB  a*inv bf16  [k][px]
  __shared__ float invs[PT];

  const int tid = threadIdx.x;
  const int n = blockIdx.x >> 3, seg = blockIdx.x & 7;
  const int wave = tid >> 6, lane = tid & 63;
  const int q = lane >> 4, pc = lane & 15;
  const int sd = tid >> 4, sc = tid & 15;          // stage: 32 rows x 16 f4x2
  const int swc = (sc * 8) ^ ((sd & 7) << 3);      // swizzled stage col
  const int rdxor = (pc & 7) << 3;                 // swizzle for GEMM2 reads

  floatx4 acc2[4][4];                // [k-tile][d-tile] = 64 regs
#pragma unroll
  for (int t = 0; t < 4; ++t)
#pragma unroll
    for (int s2 = 0; s2 < 4; ++s2) acc2[t][s2] = floatx4{0.f, 0.f, 0.f, 0.f};
  float asr[4] = {0.f, 0.f, 0.f, 0.f};   // asum partials (k = t*16+pc)

  const float* xn = x + (size_t)n * Dd * Pp;

  for (int pt = 0; pt < PXB / PT; ++pt) {
    const int p0 = seg * PXB + pt * PT;
    __syncthreads();                 // xb/a_s free to overwrite

    floatx4 acc1[4];
#pragma unroll
    for (int t = 0; t < 4; ++t) acc1[t] = floatx4{0.f, 0.f, 0.f, 0.f};
    float sq = 0.f;

    const float* xa = xn + (size_t)(q * 8) * Pp + p0 + wave * 16 + pc;
    const float* xs = xn + (size_t)sd * Pp + p0 + sc * 8;

    for (int dc = 0; dc < Dd; dc += 32) {
      // stage: re-read (L1-hot) as float4, stash bf16 tile [d][px] swizzled
      float4 u0 = *(const float4*)xs;
      float4 u1 = *(const float4*)(xs + 4);
      int2 w0 = { f2b2(u0.x, u0.y), f2b2(u0.z, u0.w) };
      int2 w1 = { f2b2(u1.x, u1.y), f2b2(u1.z, u1.w) };
      *(int2*)&xb[(dc + sd) * XS + swc] = w0;
      *(int2*)&xb[(dc + sd) * XS + swc + 4] = w1;
      xs += (size_t)32 * Pp;
      // A-frag: 8 scalar x loads (coalesced 64B segments), ssq piggyback
      float v[8];
#pragma unroll
      for (int j = 0; j < 8; ++j) {
        float a = xa[(size_t)j * Pp];
        v[j] = a; sq += a * a;
      }
      xa += (size_t)32 * Pp;
      short8 af = pack8(v);
      // B-frags from prepacked w (L2-hot) + MFMA
      const short* wc = wp + (size_t)(dc >> 5) * 2048 + pc * 32 + q * 8;
#pragma unroll
      for (int t = 0; t < 4; ++t) {
        short8 bf = *(const short8*)(wc + t * 512);
        acc1[t] = __builtin_amdgcn_mfma_f32_16x16x32_bf16(af, bf, acc1[t], 0, 0, 0);
      }
    }

    // per-pixel inv-norm (lane pc owns px = wave*16+pc partial over its q-quarter)
    {
      float tsum = sq;
      tsum += __shfl_xor(tsum, 16);
      tsum += __shfl_xor(tsum, 32);
      if (q == 0) invs[wave * 16 + pc] = 1.f / fmaxf(sqrtf(tsum), EPSF);
    }
    float ivr[4];
#pragma unroll
    for (int r = 0; r < 4; ++r) ivr[r] = invs[wave * 16 + q * 4 + r];

    // softmax over k per C-row (row = px = q*4+r, col = k = t*16+pc).
    // Max-less: |logit| <= ||w_k|| ~ 1.13, exp range [0.32, 3.1] -- safe and
    // mathematically identical to the shifted form. Fully in-wave.
#pragma unroll
    for (int r = 0; r < 4; ++r) {
      float e[4], sm = 0.f;
#pragma unroll
      for (int t = 0; t < 4; ++t) {
        e[t] = __expf(acc1[t][r] * ivr[r]);
        sm += e[t];
      }
      sm += __shfl_xor(sm, 1);
      sm += __shfl_xor(sm, 2);
      sm += __shfl_xor(sm, 4);
      sm += __shfl_xor(sm, 8);
      float si = 1.f / sm;
#pragma unroll
      for (int t = 0; t < 4; ++t) {
        float av = e[t] * si;                 // plain a
        asr[t] += av;
        as_[(t * 16 + pc) * AS + wave * 16 + q * 4 + r] = f2b1(av * ivr[r]);
      }
    }
    __syncthreads();                          // xb + a_s complete

    // GEMM2: vlad acc += a_s[k][p] * xb[d][p], all from LDS (b128 frags,
    // xb reads XOR-deswizzled: row&7 == pc&7 on both write and read sides)
#pragma unroll
    for (int c = 0; c < 4; ++c) {             // px-chunks of 32
      short8 af2[4];
#pragma unroll
      for (int t = 0; t < 4; ++t)
        af2[t] = *(const short8*)&as_[(t * 16 + pc) * AS + c * 32 + q * 8];
#pragma unroll
      for (int s2 = 0; s2 < 4; ++s2) {
        const int row = wave * 64 + s2 * 16 + pc;
        short8 bf2 = *(const short8*)&xb[row * XS + ((c * 32 + q * 8) ^ rdxor)];
#pragma unroll
        for (int t = 0; t < 4; ++t)
          acc2[t][s2] = __builtin_amdgcn_mfma_f32_16x16x32_bf16(
              af2[t], bf2, acc2[t][s2], 0, 0, 0);
      }
    }
  }

  // epilogue: asum atomics
#pragma unroll
  for (int t = 0; t < 4; ++t) {
    float v = asr[t];
    v += __shfl_xor(v, 16);
    v += __shfl_xor(v, 32);
    if (q == 0) atomicAdd(&asum[n * Kk + t * 16 + pc], v);
  }

  // epilogue: repack acc2 through xb (dead) -> row-complete short8 stores.
  // Stage layout sxb[k][d ^ ((k&7)<<3)] (xor 8-short-aligned: spreads banks,
  // preserves 16B-aligned b128 readback).
  __syncthreads();                 // all GEMM2 reads of xb done
#pragma unroll
  for (int t = 0; t < 4; ++t)
#pragma unroll
    for (int s2 = 0; s2 < 4; ++s2)
#pragma unroll
      for (int r = 0; r < 4; ++r) {
        const int k = t * 16 + q * 4 + r;
        const int d = wave * 64 + s2 * 16 + pc;
        xb[k * Dd + (d ^ ((k & 7) << 3))] = f2b1(acc2[t][s2][r]);
      }
  __syncthreads();                 // stage complete
  short* vb = vpart + ((size_t)(seg * Nn + n) * Kk) * Dd;
#pragma unroll
  for (int i = 0; i < 8; ++i) {
    const int k = i * 8 + wave;    // each wave streams rows k = i*8+wave
    const int d = lane * 8;        // 16B/lane, 1KB/instr, line-complete
    short8 val = *(const short8*)&xb[k * Dd + (d ^ ((k & 7) << 3))];
    *(short8*)&vb[(size_t)k * Dd + d] = val;
  }
}

// ---------------------------------------------------------------------------
// K2: combine 8 bf16 partials, subtract asum*centroid, intra-normalize,
// fold global 1/sqrt(K)=0.125 (rows are unit-norm after intra-normalization,
// so the global L2 norm is exactly sqrt(K)). grid: Nn*Kk blocks x 64 thr
// (1 wave: short8 16B loads, pure shfl reduction, no LDS/barrier).
// ---------------------------------------------------------------------------
__global__ __launch_bounds__(64) void k_intra(
    const short* __restrict__ vpart, const float* __restrict__ asum,
    const float* __restrict__ cent, float* __restrict__ out)
{
  const int nk = blockIdx.x;
  const int n = nk >> 6, k = nk & 63;
  const int tid = threadIdx.x;     // 0..63
  const int d = tid * 8;

  float v[8] = {0.f, 0.f, 0.f, 0.f, 0.f, 0.f, 0.f, 0.f};
#pragma unroll
  for (int ps = 0; ps < SEG; ++ps) {
    short8 t8 = *(const short8*)&vpart[((size_t)(ps * Nn + n) * Kk + k) * Dd + d];
#pragma unroll
    for (int j = 0; j < 8; ++j) v[j] += b2f(t8[j]);
  }
  float s = asum[n * Kk + k];
  float4 c0 = *(const float4*)&cent[(size_t)k * Dd + d];
  float4 c1 = *(const float4*)&cent[(size_t)k * Dd + d + 4];
  v[0] -= s * c0.x; v[1] -= s * c0.y; v[2] -= s * c0.z; v[3] -= s * c0.w;
  v[4] -= s * c1.x; v[5] -= s * c1.y; v[6] -= s * c1.z; v[7] -= s * c1.w;

  float qq = 0.f;
#pragma unroll
  for (int j = 0; j < 8; ++j) qq += v[j] * v[j];
#pragma unroll
  for (int off = 32; off; off >>= 1) qq += __shfl_xor(qq, off);
  float norm = sqrtf(qq);
  float r = 0.125f / fmaxf(norm, EPSF);   // intra-norm * global 1/sqrt(64)
  float* ob = &out[(size_t)n * (Kk * Dd) + (size_t)k * Dd + d];
  *(float4*)ob       = float4{v[0] * r, v[1] * r, v[2] * r, v[3] * r};
  *(float4*)(ob + 4) = float4{v[4] * r, v[5] * r, v[6] * r, v[7] * r};
}

extern "C" void kernel_launch(void* const* d_in, const int* in_sizes, int n_in,
                              void* d_out, int out_size, void* d_ws, size_t ws_size,
                              hipStream_t stream) {
  (void)in_sizes; (void)n_in; (void)out_size; (void)ws_size;
  const float* x    = (const float*)d_in[0];   // [N,D,H,W]
  const float* w    = (const float*)d_in[1];   // [K,D]
  const float* cent = (const float*)d_in[2];   // [K,D]
  float* out = (float*)d_out;

  // ws: asum f32[2048] | vpart bf16 [SEG*N*K*D] (16.8 MB) | wp bf16
  float* asum  = (float*)d_ws;
  short* vpart = (short*)(asum + Nn * Kk);
  short* wpk   = vpart + (size_t)SEG * Nn * Kk * Dd;

  k_wpack<<<4, 256, 0, stream>>>(w, asum, wpk);
  k_fused<<<Nn * SEG, 512, 0, stream>>>(x, wpk, asum, vpart);
  k_intra<<<Nn * Kk, 64, 0, stream>>>(vpart, asum, cent, out);
}